// Round 2
// baseline (11186.993 us; speedup 1.0000x reference)
//
#include <hip/hip_runtime.h>

#define AS1 __attribute__((address_space(1)))
#define AS3 __attribute__((address_space(3)))

typedef unsigned short u16;
typedef unsigned long long u64;
typedef __attribute__((ext_vector_type(8))) unsigned short u16x8;
typedef __attribute__((ext_vector_type(8))) __bf16 bf16x8;
typedef __attribute__((ext_vector_type(4))) float f32x4;

// problem dims
#define TT 256
#define BB 64
#define IN_DIM 2048
#define HH 1024
#define GG 4096    // 4*H
#define MM 16384   // T*B
#define NBLK 192   // 3 layers x 64 blocks

// dynamic LDS: 128KB whh fragments + pbuf[4][16][68] f32
#define WLDS_BYTES 131072
#define SMEM_BYTES (WLDS_BYTES + 4 * 16 * 68 * 4)

__device__ __forceinline__ u16 f2bf(float f) {
  unsigned u = __builtin_bit_cast(unsigned, f);
  return (u16)((u + 0x7fffu + ((u >> 16) & 1u)) >> 16);  // RNE
}
__device__ __forceinline__ float bf2f(u16 h) {
  unsigned u = ((unsigned)h) << 16;
  return __builtin_bit_cast(float, u);
}
__device__ __forceinline__ f32x4 mfma16(u16x8 a, u16x8 b, f32x4 c) {
  return __builtin_amdgcn_mfma_f32_16x16x32_bf16(
      __builtin_bit_cast(bf16x8, a), __builtin_bit_cast(bf16x8, b), c, 0, 0, 0);
}
__device__ __forceinline__ float sigmoid_fast(float x) {
  float e = __expf(-x);
  return __fdividef(1.f, 1.f + e);
}
__device__ __forceinline__ float tanh_fast(float x) {
  float xx = fmaxf(x, -30.f);
  float e = __expf(-2.f * xx);
  return __fdividef(1.f - e, 1.f + e);
}

// ---------------- prep kernels ----------------
__global__ void cvt_bf16_k(const float* __restrict__ in, u16* __restrict__ out, long n) {
  long i = ((long)blockIdx.x * blockDim.x + threadIdx.x) * 4;
  long stride = (long)gridDim.x * blockDim.x * 4;
  for (; i < n; i += stride) {
    float4 v = *(const float4*)(in + i);
    ushort4 o = { f2bf(v.x), f2bf(v.y), f2bf(v.z), f2bf(v.w) };
    *(ushort4*)(out + i) = o;
  }
}

__global__ void bias_sum_k(const float* __restrict__ a, const float* __restrict__ b,
                           float* __restrict__ o, int n) {
  int i = blockIdx.x * blockDim.x + threadIdx.x;
  if (i < n) o[i] = a[i] + b[i];
}

// ---------------- layer-0 input GEMM ----------------
// C_interleaved[m][j][g] (bf16) = A[M][K] . W[4096][K]^T + bias ; n = g*1024+j
__global__ __launch_bounds__(256) void gemm_bt_bias(
    const u16* __restrict__ A, const u16* __restrict__ W,
    const float* __restrict__ bias, u16* __restrict__ C, int K) {
  __shared__ u16 As[128 * 32];
  __shared__ u16 Bs[128 * 32];
  const int tid = threadIdx.x, wave = tid >> 6, lane = tid & 63;
  const size_t m0 = (size_t)blockIdx.x * 128, n0 = (size_t)blockIdx.y * 128;
  const int wm = (wave >> 1) * 64, wn = (wave & 1) * 64;
  const int lr = lane & 15, lq = lane >> 4;
  const int srow = wave * 16 + (lane >> 2);
  const int scol = (lane & 3) * 8;
  const u16* Ap = A + (m0 + srow) * K + scol;
  const u16* Wp = W + (n0 + srow) * K + scol;
  u16* AsB0 = &As[(wave * 64) * 8];
  u16* AsB1 = &As[(256 + wave * 64) * 8];
  u16* BsB0 = &Bs[(wave * 64) * 8];
  u16* BsB1 = &Bs[(256 + wave * 64) * 8];

  f32x4 acc[4][4];
#pragma unroll
  for (int i = 0; i < 4; ++i)
#pragma unroll
    for (int j = 0; j < 4; ++j) acc[i][j] = (f32x4){0.f, 0.f, 0.f, 0.f};

  for (int k0 = 0; k0 < K; k0 += 32) {
    __builtin_amdgcn_global_load_lds((AS1 const void*)(Ap + k0), (AS3 void*)AsB0, 16, 0, 0);
    __builtin_amdgcn_global_load_lds((AS1 const void*)(Ap + (size_t)64 * K + k0), (AS3 void*)AsB1, 16, 0, 0);
    __builtin_amdgcn_global_load_lds((AS1 const void*)(Wp + k0), (AS3 void*)BsB0, 16, 0, 0);
    __builtin_amdgcn_global_load_lds((AS1 const void*)(Wp + (size_t)64 * K + k0), (AS3 void*)BsB1, 16, 0, 0);
    __syncthreads();
    u16x8 af[4], bfr[4];
#pragma unroll
    for (int i = 0; i < 4; ++i) af[i] = *(const u16x8*)&As[(wm + i * 16 + lr) * 32 + lq * 8];
#pragma unroll
    for (int j = 0; j < 4; ++j) bfr[j] = *(const u16x8*)&Bs[(wn + j * 16 + lr) * 32 + lq * 8];
#pragma unroll
    for (int i = 0; i < 4; ++i)
#pragma unroll
      for (int j = 0; j < 4; ++j) acc[i][j] = mfma16(af[i], bfr[j], acc[i][j]);
    __syncthreads();
  }
#pragma unroll
  for (int i = 0; i < 4; ++i) {
#pragma unroll
    for (int j = 0; j < 4; ++j) {
      int n = (int)n0 + wn + j * 16 + lr;
      float bv = bias[n];
      size_t coff = (size_t)((n & 1023) * 4 + (n >> 10));
#pragma unroll
      for (int r = 0; r < 4; ++r) {
        int m = wm + i * 16 + lq * 4 + r;
        C[(m0 + m) * GG + coff] = f2bf(acc[i][j][r] + bv);
      }
    }
  }
}

// ---------------- grid barrier: relaxed arrive, relaxed poll, one acquire-fence ------
__device__ __forceinline__ void gbar(unsigned* bar) {
  __builtin_amdgcn_s_waitcnt(0);  // drain this wave's vmem (sc1 h-stores acked at coherence pt)
  __syncthreads();                // (compiler also drains all waves before s_barrier)
  if (threadIdx.x == 0) {
    unsigned g = __hip_atomic_load(&bar[1], __ATOMIC_RELAXED, __HIP_MEMORY_SCOPE_AGENT);
    unsigned a = __hip_atomic_fetch_add(&bar[0], 1u, __ATOMIC_RELAXED, __HIP_MEMORY_SCOPE_AGENT);
    if (a == NBLK - 1) {
      __hip_atomic_store(&bar[0], 0u, __ATOMIC_RELAXED, __HIP_MEMORY_SCOPE_AGENT);
      __hip_atomic_store(&bar[1], g + 1u, __ATOMIC_RELAXED, __HIP_MEMORY_SCOPE_AGENT);
    } else {
      int spins = 0;
      while (__hip_atomic_load(&bar[1], __ATOMIC_RELAXED, __HIP_MEMORY_SCOPE_AGENT) == g) {
        __builtin_amdgcn_s_sleep(2);
        if ((++spins & 63) == 0)  // progress insurance if relaxed poll caches
          (void)__hip_atomic_load(&bar[1], __ATOMIC_ACQUIRE, __HIP_MEMORY_SCOPE_AGENT);
      }
    }
  }
  __syncthreads();
  // single L1/L2 invalidate per stage: after this, normal loads see remote sc1 stores
  __builtin_amdgcn_fence(__ATOMIC_ACQUIRE, "agent");
}

// ---------------- pipelined persistent recurrence, all 3 layers ----------------
// 192 blocks x 256 thr (4 waves). layer = blk/64. Block owns 16 hidden cols j0..j0+15
// (64 gate rows). Wave w = gate g, FULL K=1024 -> no cross-wave reduce.
// W_hh slice (128KB) staged ONCE into LDS in lane-linear fragment tiles:
//   tile(g,ks) at wlds + (g*32+ks)*1024B, lane i's 16B fragment at +i*16
//   -> per-stage B reads are ds_read_b128 at base+lane*16: conflict-free, no spill.
// W_ih slice (layers 1,2): 32 x u16x8 = 128 VGPR, register-resident (cap 512, no spill).
// h exchange: hbuf[layer][slot t&1][64][1024] bf16; stores sc1 (atomic relaxed agent),
// loads normal (L2-cached) after the per-stage acquire fence.
__global__ __launch_bounds__(256, 1) void lstm_pipe(
    const u16* __restrict__ whh0, const u16* __restrict__ whh1, const u16* __restrict__ whh2,
    const u16* __restrict__ wih1, const u16* __restrict__ wih2,
    const u16* __restrict__ xgi,   // [T*B][1024][4] bf16 interleaved, bias included
    const float* __restrict__ bias,// [3][4096] (b_ih+b_hh)
    const float* __restrict__ h0,  // [3][64][1024]
    const float* __restrict__ c0,
    u16* __restrict__ hbuf,        // [3][2][64][1024] bf16
    float* __restrict__ yout,      // [T*B][1024] fp32 (layer 2)
    float* __restrict__ hTo, float* __restrict__ cTo,  // [3][64][1024]
    unsigned* __restrict__ bar) {
  extern __shared__ char smem[];
  u16* wl = (u16*)smem;                                   // 128 KB whh fragments
  float (*pbuf)[16][68] = (float(*)[16][68])(smem + WLDS_BYTES);  // [g][j16][m64+pad]

  const int tid = threadIdx.x, wave = tid >> 6, lane = tid & 63;
  const int layer = blockIdx.x >> 6;
  const int j0 = (blockIdx.x & 63) * 16;
  const int lr = lane & 15, lq = lane >> 4;
  const u16* Wh = layer == 0 ? whh0 : (layer == 1 ? whh1 : whh2);
  const u16* Wx = layer == 2 ? wih2 : wih1;

  // ---- stage whh slice -> LDS (wave w stages gate g=w, all 32 k-slices) ----
  {
    const u16* src = Wh + (size_t)(wave * 1024 + j0 + lr) * 1024 + lq * 8;
#pragma unroll
    for (int ks = 0; ks < 32; ++ks)
      __builtin_amdgcn_global_load_lds((AS1 const void*)(src + ks * 32),
                                       (AS3 void*)(wl + (size_t)(wave * 32 + ks) * 512),
                                       16, 0, 0);
  }
  // ---- wih slice -> registers (layers 1,2): 32 x u16x8 = 128 VGPR ----
  u16x8 wx[32];
  if (layer > 0) {
    const u16* src = Wx + (size_t)(wave * 1024 + j0 + lr) * 1024 + lq * 8;
#pragma unroll
    for (int ks = 0; ks < 32; ++ks) wx[ks] = *(const u16x8*)(src + ks * 32);
  }

  // pointwise mapping: thread -> m = tid>>2, j = j0 + (tid&3)*4 + d, d=0..3
  const int m = tid >> 2, jc = (tid & 3) * 4;
  float creg[4], bias_r[4][4];
#pragma unroll
  for (int d = 0; d < 4; ++d)
    creg[d] = c0[(size_t)layer * 65536 + (size_t)m * 1024 + j0 + jc + d];
  if (layer > 0) {
#pragma unroll
    for (int g = 0; g < 4; ++g)
#pragma unroll
      for (int d = 0; d < 4; ++d)
        bias_r[g][d] = bias[(size_t)layer * GG + g * 1024 + j0 + jc + d];
  }
  // init h[-1] = h0 into slot 1
  {
    u64 hp = 0;
#pragma unroll
    for (int d = 0; d < 4; ++d)
      hp |= (u64)f2bf(h0[(size_t)layer * 65536 + (size_t)m * 1024 + j0 + jc + d]) << (16 * d);
    __hip_atomic_store((u64*)(hbuf + (size_t)(layer * 2 + 1) * 65536 + (size_t)m * 1024 + j0 + jc),
                       hp, __ATOMIC_RELAXED, __HIP_MEMORY_SCOPE_AGENT);
  }
  gbar(bar);  // also drains vmcnt -> LDS staging complete

#define WL(kk) (*(const u16x8*)(wl + ((size_t)(wave * 32 + (kk)) * 64 + lane) * 8))
#define LDH(dst, kk) do { _Pragma("unroll") \
  for (int i = 0; i < 4; ++i) \
    dst[i] = *(const u16x8*)(hprev + (size_t)(i * 16 + lr) * 1024 + (kk) * 32 + lq * 8); \
  } while (0)
#define LDX(dst, kk) do { _Pragma("unroll") \
  for (int i = 0; i < 4; ++i) \
    dst[i] = *(const u16x8*)(hbel + (size_t)(i * 16 + lr) * 1024 + (kk) * 32 + lq * 8); \
  } while (0)

  for (int s = 0; s < TT + 2; ++s) {
    const int t = s - layer;
    if (t >= 0 && t < TT) {
      f32x4 acch[4], accx[4];
#pragma unroll
      for (int i = 0; i < 4; ++i) {
        acch[i] = (f32x4){0.f, 0.f, 0.f, 0.f};
        accx[i] = (f32x4){0.f, 0.f, 0.f, 0.f};
      }
      const u16* hprev = hbuf + (size_t)(layer * 2 + ((t + 1) & 1)) * 65536;  // own h[t-1]
      u16x8 xa = {}, xb = {};
      if (layer == 0) {
        // prefetch x-gate vector early; consumed after the K-loop
        const u16* xr = xgi + ((size_t)(t * BB + m)) * GG + (size_t)(j0 + jc) * 4;
        xa = *(const u16x8*)xr;
        xb = *(const u16x8*)(xr + 8);
        u16x8 a0[4], a1[4];
        LDH(a0, 0);
#pragma unroll
        for (int kk = 0; kk < 16; ++kk) {
          const int ks = kk * 2;
          LDH(a1, ks + 1);
          u16x8 b0 = WL(ks);
#pragma unroll
          for (int i = 0; i < 4; ++i) acch[i] = mfma16(a0[i], b0, acch[i]);
          if (kk < 15) LDH(a0, ks + 2);
          u16x8 b1 = WL(ks + 1);
#pragma unroll
          for (int i = 0; i < 4; ++i) accx[i] = mfma16(a1[i], b1, accx[i]);
        }
      } else {
        const u16* hbel = hbuf + (size_t)((layer - 1) * 2 + (t & 1)) * 65536;  // below h[t]
        u16x8 a0[4], b0v[4], a1[4], b1v[4];
        LDH(a0, 0); LDX(b0v, 0);
#pragma unroll
        for (int kk = 0; kk < 16; ++kk) {
          const int ks = kk * 2;
          LDH(a1, ks + 1); LDX(b1v, ks + 1);
          u16x8 bh0 = WL(ks);
#pragma unroll
          for (int i = 0; i < 4; ++i) acch[i] = mfma16(a0[i], bh0, acch[i]);
#pragma unroll
          for (int i = 0; i < 4; ++i) accx[i] = mfma16(b0v[i], wx[ks], accx[i]);
          if (kk < 15) { LDH(a0, ks + 2); LDX(b0v, ks + 2); }
          u16x8 bh1 = WL(ks + 1);
#pragma unroll
          for (int i = 0; i < 4; ++i) acch[i] = mfma16(a1[i], bh1, acch[i]);
#pragma unroll
          for (int i = 0; i < 4; ++i) accx[i] = mfma16(b1v[i], wx[ks + 1], accx[i]);
        }
      }
      // final gate pre-activations -> LDS (no cross-wave reduce needed)
#pragma unroll
      for (int i = 0; i < 4; ++i) {
        f32x4 sum = acch[i] + accx[i];
        *(f32x4*)&pbuf[wave][lr][i * 16 + lq * 4] = sum;
      }
      __syncthreads();

      float pre[4][4];  // [d][g]
#pragma unroll
      for (int g = 0; g < 4; ++g)
#pragma unroll
        for (int d = 0; d < 4; ++d)
          pre[d][g] = pbuf[g][jc + d][m];
      if (layer == 0) {
#pragma unroll
        for (int d = 0; d < 2; ++d)
#pragma unroll
          for (int g = 0; g < 4; ++g) {
            pre[d][g] += bf2f(xa[d * 4 + g]);
            pre[d + 2][g] += bf2f(xb[d * 4 + g]);
          }
      } else {
#pragma unroll
        for (int d = 0; d < 4; ++d)
#pragma unroll
          for (int g = 0; g < 4; ++g) pre[d][g] += bias_r[g][d];
      }
      float hv[4];
#pragma unroll
      for (int d = 0; d < 4; ++d) {
        float ii = sigmoid_fast(pre[d][0]);
        float ff = sigmoid_fast(pre[d][1]);
        float gg = tanh_fast(pre[d][2]);
        float oo = sigmoid_fast(pre[d][3]);
        float c = ff * creg[d] + ii * gg;
        creg[d] = c;
        hv[d] = oo * tanh_fast(c);
      }
      u64 hp = ((u64)f2bf(hv[0])) | ((u64)f2bf(hv[1]) << 16) |
               ((u64)f2bf(hv[2]) << 32) | ((u64)f2bf(hv[3]) << 48);
      __hip_atomic_store((u64*)(hbuf + (size_t)(layer * 2 + (t & 1)) * 65536 + (size_t)m * 1024 + j0 + jc),
                         hp, __ATOMIC_RELAXED, __HIP_MEMORY_SCOPE_AGENT);
      if (layer == 2) {
        float4 yv = { hv[0], hv[1], hv[2], hv[3] };
        *(float4*)(yout + ((size_t)(t * BB + m)) * 1024 + j0 + jc) = yv;
      }
      if (t == TT - 1) {
        float4 hvv = { hv[0], hv[1], hv[2], hv[3] };
        float4 cvv = { creg[0], creg[1], creg[2], creg[3] };
        *(float4*)(hTo + (size_t)layer * 65536 + (size_t)m * 1024 + j0 + jc) = hvv;
        *(float4*)(cTo + (size_t)layer * 65536 + (size_t)m * 1024 + j0 + jc) = cvv;
      }
    }
    if (s != TT + 1) gbar(bar);
  }
#undef WL
#undef LDH
#undef LDX
}

// ---------------- workspace layout ----------------
#define O_BAR   ((size_t)0)
#define O_BIAS  ((size_t)256)                        // 3*4096 f32 = 49152
#define O_HB    (O_BIAS + 49152)                     // 3*2*64*1024 bf16 = 786432
#define O_XBF   (O_HB + 786432)                      // 16384*2048 bf16 = 67108864
#define O_XGI   (O_XBF + 67108864)                   // 16384*4096 bf16 = 134217728
#define O_WIH0  (O_XGI + 134217728)                  // 16777216
#define O_WIH1  (O_WIH0 + 16777216)                  // 8388608
#define O_WIH2  (O_WIH1 + 8388608)
#define O_WHH0  (O_WIH2 + 8388608)
#define O_WHH1  (O_WHH0 + 8388608)
#define O_WHH2  (O_WHH1 + 8388608)

extern "C" void kernel_launch(void* const* d_in, const int* in_sizes, int n_in,
                              void* d_out, int out_size, void* d_ws, size_t ws_size,
                              hipStream_t stream) {
  const float* x = (const float*)d_in[0];
  const float* h0 = (const float*)d_in[1];
  const float* c0 = (const float*)d_in[2];
  char* ws = (char*)d_ws;
  unsigned* bar = (unsigned*)(ws + O_BAR);
  float* bias = (float*)(ws + O_BIAS);
  u16* hbuf = (u16*)(ws + O_HB);
  u16* xbf = (u16*)(ws + O_XBF);
  u16* xgi = (u16*)(ws + O_XGI);
  u16* wih[3] = { (u16*)(ws + O_WIH0), (u16*)(ws + O_WIH1), (u16*)(ws + O_WIH2) };
  u16* whh[3] = { (u16*)(ws + O_WHH0), (u16*)(ws + O_WHH1), (u16*)(ws + O_WHH2) };
  float* youtf = (float*)d_out;
  float* hTo = (float*)d_out + (size_t)TT * BB * HH;
  float* cTo = hTo + 3 * BB * HH;

  static int smem_set = 0;
  if (!smem_set) {
    hipFuncSetAttribute((const void*)lstm_pipe,
                        hipFuncAttributeMaxDynamicSharedMemorySize, SMEM_BYTES);
    smem_set = 1;
  }

  hipMemsetAsync(bar, 0, 256, stream);
  cvt_bf16_k<<<4096, 256, 0, stream>>>(x, xbf, (long)MM * IN_DIM);
  for (int l = 0; l < 3; ++l) {
    long wn = (long)GG * (l == 0 ? IN_DIM : HH);
    cvt_bf16_k<<<2048, 256, 0, stream>>>((const float*)d_in[3 + 4 * l], wih[l], wn);
    cvt_bf16_k<<<2048, 256, 0, stream>>>((const float*)d_in[4 + 4 * l], whh[l], (long)GG * HH);
    bias_sum_k<<<16, 256, 0, stream>>>((const float*)d_in[5 + 4 * l],
                                       (const float*)d_in[6 + 4 * l], bias + l * GG, GG);
  }
  gemm_bt_bias<<<dim3(128, 32), 256, 0, stream>>>(xbf, wih[0], bias, xgi, IN_DIM);
  lstm_pipe<<<NBLK, 256, SMEM_BYTES, stream>>>(whh[0], whh[1], whh[2], wih[1], wih[2],
                                               xgi, bias, h0, c0, hbuf, youtf, hTo, cTo, bar);
}

// Round 4
// 11114.652 us; speedup vs baseline: 1.0065x; 1.0065x over previous
//
#include <hip/hip_runtime.h>

#define AS1 __attribute__((address_space(1)))
#define AS3 __attribute__((address_space(3)))

typedef unsigned short u16;
typedef unsigned long long u64;
typedef __attribute__((ext_vector_type(8))) unsigned short u16x8;
typedef __attribute__((ext_vector_type(8))) __bf16 bf16x8;
typedef __attribute__((ext_vector_type(4))) float f32x4;

// problem dims
#define TT 256
#define BB 64
#define IN_DIM 2048
#define HH 1024
#define GG 4096    // 4*H
#define MM 16384   // T*B
#define NBLK 192   // 3 layers x 64 blocks

// dynamic LDS: 128KB whh fragments + pbuf[4][16][68] f32
#define WLDS_BYTES 131072
#define SMEM_BYTES (WLDS_BYTES + 4 * 16 * 68 * 4)

__device__ __forceinline__ u16 f2bf(float f) {
  unsigned u = __builtin_bit_cast(unsigned, f);
  return (u16)((u + 0x7fffu + ((u >> 16) & 1u)) >> 16);  // RNE
}
__device__ __forceinline__ float bf2f(u16 h) {
  unsigned u = ((unsigned)h) << 16;
  return __builtin_bit_cast(float, u);
}
__device__ __forceinline__ f32x4 mfma16(u16x8 a, u16x8 b, f32x4 c) {
  return __builtin_amdgcn_mfma_f32_16x16x32_bf16(
      __builtin_bit_cast(bf16x8, a), __builtin_bit_cast(bf16x8, b), c, 0, 0, 0);
}
__device__ __forceinline__ float sigmoid_fast(float x) {
  float e = __expf(-x);
  return __fdividef(1.f, 1.f + e);
}
__device__ __forceinline__ float tanh_fast(float x) {
  float xx = fmaxf(x, -30.f);
  float e = __expf(-2.f * xx);
  return __fdividef(1.f - e, 1.f + e);
}

// ---------------- prep kernels ----------------
__global__ void cvt_bf16_k(const float* __restrict__ in, u16* __restrict__ out, long n) {
  long i = ((long)blockIdx.x * blockDim.x + threadIdx.x) * 4;
  long stride = (long)gridDim.x * blockDim.x * 4;
  for (; i < n; i += stride) {
    float4 v = *(const float4*)(in + i);
    ushort4 o = { f2bf(v.x), f2bf(v.y), f2bf(v.z), f2bf(v.w) };
    *(ushort4*)(out + i) = o;
  }
}

__global__ void bias_sum_k(const float* __restrict__ a, const float* __restrict__ b,
                           float* __restrict__ o, int n) {
  int i = blockIdx.x * blockDim.x + threadIdx.x;
  if (i < n) o[i] = a[i] + b[i];
}

// ---------------- layer-0 input GEMM ----------------
// C_interleaved[m][j][g] (bf16) = A[M][K] . W[4096][K]^T + bias ; n = g*1024+j
__global__ __launch_bounds__(256) void gemm_bt_bias(
    const u16* __restrict__ A, const u16* __restrict__ W,
    const float* __restrict__ bias, u16* __restrict__ C, int K) {
  __shared__ u16 As[128 * 32];
  __shared__ u16 Bs[128 * 32];
  const int tid = threadIdx.x, wave = tid >> 6, lane = tid & 63;
  const size_t m0 = (size_t)blockIdx.x * 128, n0 = (size_t)blockIdx.y * 128;
  const int wm = (wave >> 1) * 64, wn = (wave & 1) * 64;
  const int lr = lane & 15, lq = lane >> 4;
  const int srow = wave * 16 + (lane >> 2);
  const int scol = (lane & 3) * 8;
  const u16* Ap = A + (m0 + srow) * K + scol;
  const u16* Wp = W + (n0 + srow) * K + scol;
  u16* AsB0 = &As[(wave * 64) * 8];
  u16* AsB1 = &As[(256 + wave * 64) * 8];
  u16* BsB0 = &Bs[(wave * 64) * 8];
  u16* BsB1 = &Bs[(256 + wave * 64) * 8];

  f32x4 acc[4][4];
#pragma unroll
  for (int i = 0; i < 4; ++i)
#pragma unroll
    for (int j = 0; j < 4; ++j) acc[i][j] = (f32x4){0.f, 0.f, 0.f, 0.f};

  for (int k0 = 0; k0 < K; k0 += 32) {
    __builtin_amdgcn_global_load_lds((AS1 const void*)(Ap + k0), (AS3 void*)AsB0, 16, 0, 0);
    __builtin_amdgcn_global_load_lds((AS1 const void*)(Ap + (size_t)64 * K + k0), (AS3 void*)AsB1, 16, 0, 0);
    __builtin_amdgcn_global_load_lds((AS1 const void*)(Wp + k0), (AS3 void*)BsB0, 16, 0, 0);
    __builtin_amdgcn_global_load_lds((AS1 const void*)(Wp + (size_t)64 * K + k0), (AS3 void*)BsB1, 16, 0, 0);
    __syncthreads();
    u16x8 af[4], bfr[4];
#pragma unroll
    for (int i = 0; i < 4; ++i) af[i] = *(const u16x8*)&As[(wm + i * 16 + lr) * 32 + lq * 8];
#pragma unroll
    for (int j = 0; j < 4; ++j) bfr[j] = *(const u16x8*)&Bs[(wn + j * 16 + lr) * 32 + lq * 8];
#pragma unroll
    for (int i = 0; i < 4; ++i)
#pragma unroll
      for (int j = 0; j < 4; ++j) acc[i][j] = mfma16(af[i], bfr[j], acc[i][j]);
    __syncthreads();
  }
#pragma unroll
  for (int i = 0; i < 4; ++i) {
#pragma unroll
    for (int j = 0; j < 4; ++j) {
      int n = (int)n0 + wn + j * 16 + lr;
      float bv = bias[n];
      size_t coff = (size_t)((n & 1023) * 4 + (n >> 10));
#pragma unroll
      for (int r = 0; r < 4; ++r) {
        int m = wm + i * 16 + lq * 4 + r;
        C[(m0 + m) * GG + coff] = f2bf(acc[i][j][r] + bv);
      }
    }
  }
}

// ---------------- pipelined persistent recurrence, all 3 layers ----------------
// 192 blocks x 256 thr (4 waves). layer = blk/64. Block owns 16 hidden cols j0..j0+15
// (64 gate rows). Wave w = gate g, FULL K=1024 -> no cross-wave reduce.
// W_hh slice (128KB) staged ONCE into LDS (lane-linear fragment tiles, conflict-free).
// W_ih slice (layers 1,2): 32 NAMED u16x8 register variables (128 VGPR), macro-unrolled
// K-loop with literal indices only -> no spill under launch_bounds(256,1) (512 VGPR cap).
// Sync: monotonic per-block flags flag[l][64] (no lockstep barrier):
//   flag[l][b] = # h vectors published by block b of layer l (h0 counts as 1;
//   after step t it becomes t+2). Block of layer l at step t waits:
//     flag[l][*]   >= t+1   (peers stored h[t-1]; covers own slot anti-dep)
//     flag[l-1][*] >= t+2   (below stored h[t])                       [l>0]
//     flag[l+1][*] >= t     (above consumed h[t-2] before slot reuse) [l<2]
//   ONLY WAVE 0 POLLS (anti poll-storm: 1/4 the fabric traffic of all-wave polling;
//   round-3 hang suspect); other waves park at __syncthreads. s_sleep(4) between polls.
//   Producer: h stores (sc1) -> s_waitcnt(0) -> __syncthreads -> tid0 flag store.
//   Consumer: wave0 relaxed polls -> __syncthreads -> one agent acquire fence (all waves).
__global__ __launch_bounds__(256, 1) void lstm_pipe(
    const u16* __restrict__ whh0, const u16* __restrict__ whh1, const u16* __restrict__ whh2,
    const u16* __restrict__ wih1, const u16* __restrict__ wih2,
    const u16* __restrict__ xgi,   // [T*B][1024][4] bf16 interleaved, bias included
    const float* __restrict__ bias,// [3][4096] (b_ih+b_hh)
    const float* __restrict__ h0,  // [3][64][1024]
    const float* __restrict__ c0,
    u16* __restrict__ hbuf,        // [3][2][64][1024] bf16
    float* __restrict__ yout,      // [T*B][1024] fp32 (layer 2)
    float* __restrict__ hTo, float* __restrict__ cTo,  // [3][64][1024]
    unsigned* __restrict__ flags) {
  extern __shared__ char smem[];
  u16* wl = (u16*)smem;                                   // 128 KB whh fragments
  float (*pbuf)[16][68] = (float(*)[16][68])(smem + WLDS_BYTES);  // [g][j16][m64+pad]

  const int tid = threadIdx.x, wave = tid >> 6, lane = tid & 63;
  const int layer = blockIdx.x >> 6;
  const int blk = blockIdx.x & 63;
  const int j0 = blk * 16;
  const int lr = lane & 15, lq = lane >> 4;
  const u16* Wh = layer == 0 ? whh0 : (layer == 1 ? whh1 : whh2);
  const u16* Wx = layer == 2 ? wih2 : wih1;

  // ---- stage whh slice -> LDS (wave w stages gate g=w, all 32 k-slices) ----
  {
    const u16* src = Wh + (size_t)(wave * 1024 + j0 + lr) * 1024 + lq * 8;
#pragma unroll
    for (int ks = 0; ks < 32; ++ks)
      __builtin_amdgcn_global_load_lds((AS1 const void*)(src + ks * 32),
                                       (AS3 void*)(wl + (size_t)(wave * 32 + ks) * 512),
                                       16, 0, 0);
  }
  // ---- wih slice -> 32 named register variables (layers 1,2; layer0 loads whh0, DCE'd) --
  const u16* wxsrc = (layer > 0 ? Wx : Wh) + (size_t)(wave * 1024 + j0 + lr) * 1024 + lq * 8;
#define WXD(k) u16x8 wx##k;
#define WXL(k) wx##k = *(const u16x8*)(wxsrc + (k) * 32);
#define REP32(M) M(0) M(1) M(2) M(3) M(4) M(5) M(6) M(7) M(8) M(9) M(10) M(11) \
  M(12) M(13) M(14) M(15) M(16) M(17) M(18) M(19) M(20) M(21) M(22) M(23) \
  M(24) M(25) M(26) M(27) M(28) M(29) M(30) M(31)
#define REPP(M) M(0,1) M(2,3) M(4,5) M(6,7) M(8,9) M(10,11) M(12,13) M(14,15) \
  M(16,17) M(18,19) M(20,21) M(22,23) M(24,25) M(26,27) M(28,29) M(30,31)
  REP32(WXD)
  REP32(WXL)

  // pointwise mapping: thread -> m = tid>>2, j = j0 + (tid&3)*4 + d, d=0..3
  const int m = tid >> 2, jc = (tid & 3) * 4;
  float creg[4], bias_r[4][4];
#pragma unroll
  for (int d = 0; d < 4; ++d)
    creg[d] = c0[(size_t)layer * 65536 + (size_t)m * 1024 + j0 + jc + d];
  if (layer > 0) {
#pragma unroll
    for (int g = 0; g < 4; ++g)
#pragma unroll
      for (int d = 0; d < 4; ++d)
        bias_r[g][d] = bias[(size_t)layer * GG + g * 1024 + j0 + jc + d];
  }
  // init h[-1] = h0 into slot 1, then publish flag=1
  {
    u64 hp = 0;
#pragma unroll
    for (int d = 0; d < 4; ++d)
      hp |= (u64)f2bf(h0[(size_t)layer * 65536 + (size_t)m * 1024 + j0 + jc + d]) << (16 * d);
    __hip_atomic_store((u64*)(hbuf + (size_t)(layer * 2 + 1) * 65536 + (size_t)m * 1024 + j0 + jc),
                       hp, __ATOMIC_RELAXED, __HIP_MEMORY_SCOPE_AGENT);
  }
  __builtin_amdgcn_s_waitcnt(0);   // drains h0 store + LDS staging + wx loads (this wave)
  __syncthreads();                 // all waves drained
  if (tid == 0)
    __hip_atomic_store(&flags[layer * 64 + blk], 1u, __ATOMIC_RELAXED, __HIP_MEMORY_SCOPE_AGENT);

#define WL(kk) (*(const u16x8*)(wl + ((size_t)(wave * 32 + (kk)) * 64 + lane) * 8))
#define LDH(dst, kk) do { _Pragma("unroll") \
  for (int i = 0; i < 4; ++i) \
    dst[i] = *(const u16x8*)(hprev + (size_t)(i * 16 + lr) * 1024 + (kk) * 32 + lq * 8); \
  } while (0)
#define LDX(dst, kk) do { _Pragma("unroll") \
  for (int i = 0; i < 4; ++i) \
    dst[i] = *(const u16x8*)(hbel + (size_t)(i * 16 + lr) * 1024 + (kk) * 32 + lq * 8); \
  } while (0)
// fused pair: h-slice from LDS whh, x-slice from register wx; distance-1 prefetch
#define KPAIR(ke, ko) { \
    LDH(ha1, ko); LDX(xb1, ko); \
    { u16x8 bh = WL(ke); \
      _Pragma("unroll") for (int i = 0; i < 4; ++i) acch[i] = mfma16(ha0[i], bh, acch[i]); } \
    _Pragma("unroll") for (int i = 0; i < 4; ++i) accx[i] = mfma16(xb0[i], wx##ke, accx[i]); \
    if ((ko) < 31) { LDH(ha0, (ko) + 1); LDX(xb0, (ko) + 1); } \
    { u16x8 bh = WL(ko); \
      _Pragma("unroll") for (int i = 0; i < 4; ++i) acch[i] = mfma16(ha1[i], bh, acch[i]); } \
    _Pragma("unroll") for (int i = 0; i < 4; ++i) accx[i] = mfma16(xb1[i], wx##ko, accx[i]); \
  }
#define K0PAIR(ke, ko) { \
    LDH(ha1, ko); \
    { u16x8 bh = WL(ke); \
      _Pragma("unroll") for (int i = 0; i < 4; ++i) acch[i] = mfma16(ha0[i], bh, acch[i]); } \
    if ((ko) < 31) LDH(ha0, (ko) + 1); \
    { u16x8 bh = WL(ko); \
      _Pragma("unroll") for (int i = 0; i < 4; ++i) acch[i] = mfma16(ha1[i], bh, acch[i]); } \
  }

  for (int t = 0; t < TT; ++t) {
    // xgi prefetch (layer 0): issue before the poll so latency hides under it
    u16x8 xa = {}, xb = {};
    if (layer == 0) {
      const u16* xr = xgi + ((size_t)(t * BB + m)) * GG + (size_t)(j0 + jc) * 4;
      xa = *(const u16x8*)xr;
      xb = *(const u16x8*)(xr + 8);
    }
    // ---- dependency poll: WAVE 0 ONLY (lane-parallel over 64 peer blocks) ----
    if (wave == 0) {
      int spins = 0;
      for (;;) {
        unsigned vo = __hip_atomic_load(&flags[layer * 64 + lane],
                                        __ATOMIC_RELAXED, __HIP_MEMORY_SCOPE_AGENT);
        bool ok = vo >= (unsigned)(t + 1);
        if (layer > 0) {
          unsigned vb = __hip_atomic_load(&flags[(layer - 1) * 64 + lane],
                                          __ATOMIC_RELAXED, __HIP_MEMORY_SCOPE_AGENT);
          ok = ok && (vb >= (unsigned)(t + 2));
        }
        if (layer < 2) {
          unsigned va = __hip_atomic_load(&flags[(layer + 1) * 64 + lane],
                                          __ATOMIC_RELAXED, __HIP_MEMORY_SCOPE_AGENT);
          ok = ok && (va >= (unsigned)t);
        }
        if (__all(ok)) break;
        __builtin_amdgcn_s_sleep(4);
        if ((++spins & 31) == 0)  // progress insurance if relaxed poll caches
          (void)__hip_atomic_load(&flags[layer * 64 + lane],
                                  __ATOMIC_ACQUIRE, __HIP_MEMORY_SCOPE_AGENT);
      }
    }
    __syncthreads();  // waves 1-3 wait here, zero fabric traffic
    // make remote sc1 h-stores visible to normal loads (per-wave L1/L2 invalidate)
    __builtin_amdgcn_fence(__ATOMIC_ACQUIRE, "agent");

    f32x4 acch[4], accx[4];
#pragma unroll
    for (int i = 0; i < 4; ++i) {
      acch[i] = (f32x4){0.f, 0.f, 0.f, 0.f};
      accx[i] = (f32x4){0.f, 0.f, 0.f, 0.f};
    }
    const u16* hprev = hbuf + (size_t)(layer * 2 + ((t + 1) & 1)) * 65536;  // own h[t-1]
    if (layer == 0) {
      u16x8 ha0[4], ha1[4];
      LDH(ha0, 0);
      REPP(K0PAIR)
    } else {
      const u16* hbel = hbuf + (size_t)((layer - 1) * 2 + (t & 1)) * 65536;  // below h[t]
      u16x8 ha0[4], ha1[4], xb0[4], xb1[4];
      LDH(ha0, 0); LDX(xb0, 0);
      REPP(KPAIR)
    }
    // gate pre-activations -> LDS (wave owns one gate, full K)
#pragma unroll
    for (int i = 0; i < 4; ++i) {
      f32x4 sum = acch[i] + accx[i];
      *(f32x4*)&pbuf[wave][lr][i * 16 + lq * 4] = sum;
    }
    __syncthreads();

    float pre[4][4];  // [d][g]
#pragma unroll
    for (int g = 0; g < 4; ++g)
#pragma unroll
      for (int d = 0; d < 4; ++d)
        pre[d][g] = pbuf[g][jc + d][m];
    if (layer == 0) {
#pragma unroll
      for (int d = 0; d < 2; ++d)
#pragma unroll
        for (int g = 0; g < 4; ++g) {
          pre[d][g] += bf2f(xa[d * 4 + g]);
          pre[d + 2][g] += bf2f(xb[d * 4 + g]);
        }
    } else {
#pragma unroll
      for (int d = 0; d < 4; ++d)
#pragma unroll
        for (int g = 0; g < 4; ++g) pre[d][g] += bias_r[g][d];
    }
    float hv[4];
#pragma unroll
    for (int d = 0; d < 4; ++d) {
      float ii = sigmoid_fast(pre[d][0]);
      float ff = sigmoid_fast(pre[d][1]);
      float gg = tanh_fast(pre[d][2]);
      float oo = sigmoid_fast(pre[d][3]);
      float c = ff * creg[d] + ii * gg;
      creg[d] = c;
      hv[d] = oo * tanh_fast(c);
    }
    u64 hp = ((u64)f2bf(hv[0])) | ((u64)f2bf(hv[1]) << 16) |
             ((u64)f2bf(hv[2]) << 32) | ((u64)f2bf(hv[3]) << 48);
    __hip_atomic_store((u64*)(hbuf + (size_t)(layer * 2 + (t & 1)) * 65536 + (size_t)m * 1024 + j0 + jc),
                       hp, __ATOMIC_RELAXED, __HIP_MEMORY_SCOPE_AGENT);
    if (layer == 2) {
      float4 yv = { hv[0], hv[1], hv[2], hv[3] };
      *(float4*)(yout + ((size_t)(t * BB + m)) * 1024 + j0 + jc) = yv;
    }
    if (t == TT - 1) {
      float4 hvv = { hv[0], hv[1], hv[2], hv[3] };
      float4 cvv = { creg[0], creg[1], creg[2], creg[3] };
      *(float4*)(hTo + (size_t)layer * 65536 + (size_t)m * 1024 + j0 + jc) = hvv;
      *(float4*)(cTo + (size_t)layer * 65536 + (size_t)m * 1024 + j0 + jc) = cvv;
    }
    // ---- publish: h stores drained on every wave, then one flag store ----
    __builtin_amdgcn_s_waitcnt(0);
    __syncthreads();   // also protects pbuf reuse next stage
    if (tid == 0)
      __hip_atomic_store(&flags[layer * 64 + blk], (unsigned)(t + 2),
                         __ATOMIC_RELAXED, __HIP_MEMORY_SCOPE_AGENT);
  }
#undef WL
#undef LDH
#undef LDX
#undef KPAIR
#undef K0PAIR
#undef WXD
#undef WXL
#undef REP32
#undef REPP
}

// ---------------- workspace layout ----------------
#define O_FLAGS ((size_t)0)                          // 3*64 u32 = 768, pad to 1024
#define O_BIAS  ((size_t)1024)                       // 3*4096 f32 = 49152
#define O_HB    (O_BIAS + 49152)                     // 3*2*64*1024 bf16 = 786432
#define O_XBF   (O_HB + 786432)                      // 16384*2048 bf16 = 67108864
#define O_XGI   (O_XBF + 67108864)                   // 16384*4096 bf16 = 134217728
#define O_WIH0  (O_XGI + 134217728)                  // 16777216
#define O_WIH1  (O_WIH0 + 16777216)                  // 8388608
#define O_WIH2  (O_WIH1 + 8388608)
#define O_WHH0  (O_WIH2 + 8388608)
#define O_WHH1  (O_WHH0 + 8388608)
#define O_WHH2  (O_WHH1 + 8388608)

extern "C" void kernel_launch(void* const* d_in, const int* in_sizes, int n_in,
                              void* d_out, int out_size, void* d_ws, size_t ws_size,
                              hipStream_t stream) {
  const float* x = (const float*)d_in[0];
  const float* h0 = (const float*)d_in[1];
  const float* c0 = (const float*)d_in[2];
  char* ws = (char*)d_ws;
  unsigned* flags = (unsigned*)(ws + O_FLAGS);
  float* bias = (float*)(ws + O_BIAS);
  u16* hbuf = (u16*)(ws + O_HB);
  u16* xbf = (u16*)(ws + O_XBF);
  u16* xgi = (u16*)(ws + O_XGI);
  u16* wih[3] = { (u16*)(ws + O_WIH0), (u16*)(ws + O_WIH1), (u16*)(ws + O_WIH2) };
  u16* whh[3] = { (u16*)(ws + O_WHH0), (u16*)(ws + O_WHH1), (u16*)(ws + O_WHH2) };
  float* youtf = (float*)d_out;
  float* hTo = (float*)d_out + (size_t)TT * BB * HH;
  float* cTo = hTo + 3 * BB * HH;

  static int smem_set = 0;
  if (!smem_set) {
    hipFuncSetAttribute((const void*)lstm_pipe,
                        hipFuncAttributeMaxDynamicSharedMemorySize, SMEM_BYTES);
    smem_set = 1;
  }

  hipMemsetAsync(flags, 0, 1024, stream);
  cvt_bf16_k<<<4096, 256, 0, stream>>>(x, xbf, (long)MM * IN_DIM);
  for (int l = 0; l < 3; ++l) {
    long wn = (long)GG * (l == 0 ? IN_DIM : HH);
    cvt_bf16_k<<<2048, 256, 0, stream>>>((const float*)d_in[3 + 4 * l], wih[l], wn);
    cvt_bf16_k<<<2048, 256, 0, stream>>>((const float*)d_in[4 + 4 * l], whh[l], (long)GG * HH);
    bias_sum_k<<<16, 256, 0, stream>>>((const float*)d_in[5 + 4 * l],
                                       (const float*)d_in[6 + 4 * l], bias + l * GG, GG);
  }
  gemm_bt_bias<<<dim3(128, 32), 256, 0, stream>>>(xbf, wih[0], bias, xgi, IN_DIM);
  lstm_pipe<<<NBLK, 256, SMEM_BYTES, stream>>>(whh[0], whh[1], whh[2], wih[1], wih[2],
                                               xgi, bias, h0, c0, hbuf, youtf, hTo, cTo, flags);
}

// Round 6
// 10096.992 us; speedup vs baseline: 1.1080x; 1.1008x over previous
//
#include <hip/hip_runtime.h>

#define AS1 __attribute__((address_space(1)))
#define AS3 __attribute__((address_space(3)))

typedef unsigned short u16;
typedef unsigned long long u64;
typedef __attribute__((ext_vector_type(8))) unsigned short u16x8;
typedef __attribute__((ext_vector_type(2))) unsigned long long u64x2;
typedef __attribute__((ext_vector_type(8))) __bf16 bf16x8;
typedef __attribute__((ext_vector_type(4))) float f32x4;

// problem dims
#define TT 256
#define BB 64
#define IN_DIM 2048
#define HH 1024
#define GG 4096    // 4*H
#define MM 16384   // T*B
#define NBLK 192   // 3 layers x 64 blocks

// dynamic LDS: 128KB whh fragment tiles + per-wave transpose buf [4][4][16][20] f32
#define WLDS_BYTES 131072
#define PB_STRIDE 20
#define SMEM_BYTES (WLDS_BYTES + 4 * 4 * 16 * PB_STRIDE * 4)

__device__ __forceinline__ u16 f2bf(float f) {
  unsigned u = __builtin_bit_cast(unsigned, f);
  return (u16)((u + 0x7fffu + ((u >> 16) & 1u)) >> 16);  // RNE
}
__device__ __forceinline__ float bf2f(u16 h) {
  unsigned u = ((unsigned)h) << 16;
  return __builtin_bit_cast(float, u);
}
__device__ __forceinline__ f32x4 mfma16(u16x8 a, u16x8 b, f32x4 c) {
  return __builtin_amdgcn_mfma_f32_16x16x32_bf16(
      __builtin_bit_cast(bf16x8, a), __builtin_bit_cast(bf16x8, b), c, 0, 0, 0);
}
__device__ __forceinline__ float sigmoid_fast(float x) {
  float e = __expf(-x);
  return __fdividef(1.f, 1.f + e);
}
__device__ __forceinline__ float tanh_fast(float x) {
  float xx = fmaxf(x, -30.f);
  float e = __expf(-2.f * xx);
  return __fdividef(1.f - e, 1.f + e);
}
// agent-coherent 16B h-load as 2x u64 relaxed agent atomic loads: serviced at the
// coherence point (sees remote sc1 stores, NO fence needed), compiler-managed waits.
__device__ __forceinline__ u16x8 ld_h16(const u16* p) {
  u64 lo = __hip_atomic_load((const u64*)p, __ATOMIC_RELAXED, __HIP_MEMORY_SCOPE_AGENT);
  u64 hi = __hip_atomic_load((const u64*)(p + 4), __ATOMIC_RELAXED, __HIP_MEMORY_SCOPE_AGENT);
  u64x2 v = { lo, hi };
  return __builtin_bit_cast(u16x8, v);
}

// ---------------- prep kernels ----------------
__global__ void cvt_bf16_k(const float* __restrict__ in, u16* __restrict__ out, long n) {
  long i = ((long)blockIdx.x * blockDim.x + threadIdx.x) * 4;
  long stride = (long)gridDim.x * blockDim.x * 4;
  for (; i < n; i += stride) {
    float4 v = *(const float4*)(in + i);
    ushort4 o = { f2bf(v.x), f2bf(v.y), f2bf(v.z), f2bf(v.w) };
    *(ushort4*)(out + i) = o;
  }
}

__global__ void bias_sum_k(const float* __restrict__ a, const float* __restrict__ b,
                           float* __restrict__ o, int n) {
  int i = blockIdx.x * blockDim.x + threadIdx.x;
  if (i < n) o[i] = a[i] + b[i];
}

// ---------------- layer-0 input GEMM ----------------
// C_interleaved[m][j][g] (bf16) = A[M][K] . W[4096][K]^T + bias ; n = g*1024+j
__global__ __launch_bounds__(256) void gemm_bt_bias(
    const u16* __restrict__ A, const u16* __restrict__ W,
    const float* __restrict__ bias, u16* __restrict__ C, int K) {
  __shared__ u16 As[128 * 32];
  __shared__ u16 Bs[128 * 32];
  const int tid = threadIdx.x, wave = tid >> 6, lane = tid & 63;
  const size_t m0 = (size_t)blockIdx.x * 128, n0 = (size_t)blockIdx.y * 128;
  const int wm = (wave >> 1) * 64, wn = (wave & 1) * 64;
  const int lr = lane & 15, lq = lane >> 4;
  const int srow = wave * 16 + (lane >> 2);
  const int scol = (lane & 3) * 8;
  const u16* Ap = A + (m0 + srow) * K + scol;
  const u16* Wp = W + (n0 + srow) * K + scol;
  u16* AsB0 = &As[(wave * 64) * 8];
  u16* AsB1 = &As[(256 + wave * 64) * 8];
  u16* BsB0 = &Bs[(wave * 64) * 8];
  u16* BsB1 = &Bs[(256 + wave * 64) * 8];

  f32x4 acc[4][4];
#pragma unroll
  for (int i = 0; i < 4; ++i)
#pragma unroll
    for (int j = 0; j < 4; ++j) acc[i][j] = (f32x4){0.f, 0.f, 0.f, 0.f};

  for (int k0 = 0; k0 < K; k0 += 32) {
    __builtin_amdgcn_global_load_lds((AS1 const void*)(Ap + k0), (AS3 void*)AsB0, 16, 0, 0);
    __builtin_amdgcn_global_load_lds((AS1 const void*)(Ap + (size_t)64 * K + k0), (AS3 void*)AsB1, 16, 0, 0);
    __builtin_amdgcn_global_load_lds((AS1 const void*)(Wp + k0), (AS3 void*)BsB0, 16, 0, 0);
    __builtin_amdgcn_global_load_lds((AS1 const void*)(Wp + (size_t)64 * K + k0), (AS3 void*)BsB1, 16, 0, 0);
    __syncthreads();
    u16x8 af[4], bfr[4];
#pragma unroll
    for (int i = 0; i < 4; ++i) af[i] = *(const u16x8*)&As[(wm + i * 16 + lr) * 32 + lq * 8];
#pragma unroll
    for (int j = 0; j < 4; ++j) bfr[j] = *(const u16x8*)&Bs[(wn + j * 16 + lr) * 32 + lq * 8];
#pragma unroll
    for (int i = 0; i < 4; ++i)
#pragma unroll
      for (int j = 0; j < 4; ++j) acc[i][j] = mfma16(af[i], bfr[j], acc[i][j]);
    __syncthreads();
  }
#pragma unroll
  for (int i = 0; i < 4; ++i) {
#pragma unroll
    for (int j = 0; j < 4; ++j) {
      int n = (int)n0 + wn + j * 16 + lr;
      float bv = bias[n];
      size_t coff = (size_t)((n & 1023) * 4 + (n >> 10));
#pragma unroll
      for (int r = 0; r < 4; ++r) {
        int m = wm + i * 16 + lq * 4 + r;
        C[(m0 + m) * GG + coff] = f2bf(acc[i][j][r] + bv);
      }
    }
  }
}

// ---------------- pipelined persistent recurrence, all 3 layers ----------------
// 192 blocks x 256 thr (4 waves). layer = blk/64. Block owns 16 hidden cols j0..j0+15
// (64 gate rows). Wave = BATCH-QUARTER: 16 batch rows, FULL K=1024, all 4 gates
// -> h read exactly once per block AND no cross-wave reduce (per-wave LDS transpose only,
// same-wave ds write->read, no barrier).
// W_hh slice (128 KB) staged ONCE into LDS, lane-linear conflict-free fragment tiles.
// W_ih (layers 1,2) + xgi + bias: written before launch -> NORMAL cached loads; since
// there is NO acquire fence anywhere in the loop, L2 stays warm across all 256 stages.
// h (the only in-loop cross-block data): u64 relaxed AGENT atomic loads (coherent at
// MALL, no fence) batched 8 fragments ahead in a 2-deep chunk pipeline.
// Sync: monotonic per-block flags flag[l][64] (round-4 proven):
//   flag[l][b] = # h vectors published (h0 counts as 1; after step t -> t+2).
//   At step t wait: flag[l][*]>=t+1, flag[l-1][*]>=t+2 (l>0), flag[l+1][*]>=t (l<2).
//   Wave 0 polls (relaxed agent atomic loads + periodic acquire insurance);
//   waves 1-3 park at __syncthreads.
//   Producer: h stores (sc1) -> s_waitcnt(0) -> __syncthreads -> tid0 flag store.
__global__ __launch_bounds__(256, 1) void lstm_pipe(
    const u16* __restrict__ whh0, const u16* __restrict__ whh1, const u16* __restrict__ whh2,
    const u16* __restrict__ wih1, const u16* __restrict__ wih2,
    const u16* __restrict__ xgi,   // [T*B][1024][4] bf16 interleaved, bias included
    const float* __restrict__ bias,// [3][4096] (b_ih+b_hh)
    const float* __restrict__ h0,  // [3][64][1024]
    const float* __restrict__ c0,
    u16* __restrict__ hbuf,        // [3][2][64][1024] bf16
    float* __restrict__ yout,      // [T*B][1024] fp32 (layer 2)
    float* __restrict__ hTo, float* __restrict__ cTo,  // [3][64][1024]
    unsigned* __restrict__ flags) {
  extern __shared__ char smem[];
  u16* wl = (u16*)smem;                          // 128 KB whh tiles
  float* pb = (float*)(smem + WLDS_BYTES);       // [4 wave][4 g][16 j][20] transpose buf

  const int tid = threadIdx.x, wave = tid >> 6, lane = tid & 63;
  const int layer = blockIdx.x >> 6;
  const int blk = blockIdx.x & 63;
  const int j0 = blk * 16;
  const int lr = lane & 15, lq = lane >> 4;
  const u16* Wh = layer == 0 ? whh0 : (layer == 1 ? whh1 : whh2);
  const u16* Wx = layer == 2 ? wih2 : wih1;

  // ---- stage whh slice -> LDS: fragment f=(g*32+ks) at wl + f*512 u16, lane's 16B at
  //      +lane*8 u16 (global_load_lds writes lane-linear). wave w stages gate g=w. ----
#pragma unroll
  for (int ks = 0; ks < 32; ++ks) {
    const u16* src = Wh + (size_t)(wave * 1024 + j0 + lr) * 1024 + ks * 32 + lq * 8;
    __builtin_amdgcn_global_load_lds((AS1 const void*)src,
                                     (AS3 void*)(wl + (size_t)(wave * 32 + ks) * 512),
                                     16, 0, 0);
  }

  // pointwise mapping: thread -> m = wave*16 + (lane>>2), j = j0 + (lane&3)*4 + d
  const int m_loc = lane >> 2, jc = (lane & 3) * 4;
  const int m = wave * 16 + m_loc;
  float creg[4], bias_r[4][4];
#pragma unroll
  for (int d = 0; d < 4; ++d)
    creg[d] = c0[(size_t)layer * 65536 + (size_t)m * 1024 + j0 + jc + d];
  if (layer > 0) {
#pragma unroll
    for (int g = 0; g < 4; ++g)
#pragma unroll
      for (int d = 0; d < 4; ++d)
        bias_r[g][d] = bias[(size_t)layer * GG + g * 1024 + j0 + jc + d];
  }
  // init h[-1] = h0 into slot 1, then publish flag=1
  {
    u64 hp0 = 0;
#pragma unroll
    for (int d = 0; d < 4; ++d)
      hp0 |= (u64)f2bf(h0[(size_t)layer * 65536 + (size_t)m * 1024 + j0 + jc + d]) << (16 * d);
    __hip_atomic_store((u64*)(hbuf + (size_t)(layer * 2 + 1) * 65536 + (size_t)m * 1024 + j0 + jc),
                       hp0, __ATOMIC_RELAXED, __HIP_MEMORY_SCOPE_AGENT);
  }
  __builtin_amdgcn_s_waitcnt(0);   // drain h0 store + LDS staging
  __syncthreads();
  if (tid == 0)
    __hip_atomic_store(&flags[layer * 64 + blk], 1u, __ATOMIC_RELAXED, __HIP_MEMORY_SCOPE_AGENT);

  // wih per-gate lane base (loop-invariant; normal loads -> L2-warm, no fence ever)
  const u16* wxp = Wx + (size_t)(j0 + lr) * 1024 + lq * 8;

#define WL(g, ks) (*(const u16x8*)(wl + ((size_t)((g) * 32 + (ks)) * 64 + lane) * 8))

#define DECLH(S) u16x8 S##h0, S##h1, S##h2, S##h3, S##h4, S##h5, S##h6, S##h7;
#define DECLX(S) u16x8 S##x0, S##x1, S##x2, S##x3, S##x4, S##x5, S##x6, S##x7;
#define LH(S, c) \
  S##h0 = ld_h16(hp + ((c) * 8 + 0) * 32); S##h1 = ld_h16(hp + ((c) * 8 + 1) * 32); \
  S##h2 = ld_h16(hp + ((c) * 8 + 2) * 32); S##h3 = ld_h16(hp + ((c) * 8 + 3) * 32); \
  S##h4 = ld_h16(hp + ((c) * 8 + 4) * 32); S##h5 = ld_h16(hp + ((c) * 8 + 5) * 32); \
  S##h6 = ld_h16(hp + ((c) * 8 + 6) * 32); S##h7 = ld_h16(hp + ((c) * 8 + 7) * 32);
#define LX(S, c) \
  S##x0 = ld_h16(xp + ((c) * 8 + 0) * 32); S##x1 = ld_h16(xp + ((c) * 8 + 1) * 32); \
  S##x2 = ld_h16(xp + ((c) * 8 + 2) * 32); S##x3 = ld_h16(xp + ((c) * 8 + 3) * 32); \
  S##x4 = ld_h16(xp + ((c) * 8 + 4) * 32); S##x5 = ld_h16(xp + ((c) * 8 + 5) * 32); \
  S##x6 = ld_h16(xp + ((c) * 8 + 6) * 32); S##x7 = ld_h16(xp + ((c) * 8 + 7) * 32);
#define CKH(S, kk, ks) { \
  u16x8 b0 = WL(0, ks), b1 = WL(1, ks), b2 = WL(2, ks), b3 = WL(3, ks); \
  acch[0] = mfma16(S##h##kk, b0, acch[0]); acch[1] = mfma16(S##h##kk, b1, acch[1]); \
  acch[2] = mfma16(S##h##kk, b2, acch[2]); acch[3] = mfma16(S##h##kk, b3, acch[3]); }
#define CKX(S, kk, ks) { \
  u16x8 w0 = *(const u16x8*)(wxp + (size_t)(ks) * 32); \
  u16x8 w1 = *(const u16x8*)(wxp + 1048576 + (size_t)(ks) * 32); \
  u16x8 w2 = *(const u16x8*)(wxp + 2097152 + (size_t)(ks) * 32); \
  u16x8 w3 = *(const u16x8*)(wxp + 3145728 + (size_t)(ks) * 32); \
  accx[0] = mfma16(S##x##kk, w0, accx[0]); accx[1] = mfma16(S##x##kk, w1, accx[1]); \
  accx[2] = mfma16(S##x##kk, w2, accx[2]); accx[3] = mfma16(S##x##kk, w3, accx[3]); }
#define CC8H(S, c) \
  CKH(S, 0, (c) * 8 + 0) CKH(S, 1, (c) * 8 + 1) CKH(S, 2, (c) * 8 + 2) CKH(S, 3, (c) * 8 + 3) \
  CKH(S, 4, (c) * 8 + 4) CKH(S, 5, (c) * 8 + 5) CKH(S, 6, (c) * 8 + 6) CKH(S, 7, (c) * 8 + 7)
#define CC8HX(S, c) \
  CKH(S, 0, (c) * 8 + 0) CKX(S, 0, (c) * 8 + 0) CKH(S, 1, (c) * 8 + 1) CKX(S, 1, (c) * 8 + 1) \
  CKH(S, 2, (c) * 8 + 2) CKX(S, 2, (c) * 8 + 2) CKH(S, 3, (c) * 8 + 3) CKX(S, 3, (c) * 8 + 3) \
  CKH(S, 4, (c) * 8 + 4) CKX(S, 4, (c) * 8 + 4) CKH(S, 5, (c) * 8 + 5) CKX(S, 5, (c) * 8 + 5) \
  CKH(S, 6, (c) * 8 + 6) CKX(S, 6, (c) * 8 + 6) CKH(S, 7, (c) * 8 + 7) CKX(S, 7, (c) * 8 + 7)

  for (int t = 0; t < TT; ++t) {
    // xgi prefetch (layer 0): static data; issue before the poll to hide latency
    u16x8 xa = {}, xb = {};
    if (layer == 0) {
      const u16* xr = xgi + ((size_t)(t * BB + m)) * GG + (size_t)(j0 + jc) * 4;
      xa = *(const u16x8*)xr;
      xb = *(const u16x8*)(xr + 8);
    }
    // ---- dependency poll: WAVE 0 ONLY; other waves park at the barrier ----
    if (wave == 0) {
      int spins = 0;
      for (;;) {
        unsigned vo = __hip_atomic_load(&flags[layer * 64 + lane],
                                        __ATOMIC_RELAXED, __HIP_MEMORY_SCOPE_AGENT);
        bool ok = vo >= (unsigned)(t + 1);
        if (layer > 0) {
          unsigned vb = __hip_atomic_load(&flags[(layer - 1) * 64 + lane],
                                          __ATOMIC_RELAXED, __HIP_MEMORY_SCOPE_AGENT);
          ok = ok && (vb >= (unsigned)(t + 2));
        }
        if (layer < 2) {
          unsigned va = __hip_atomic_load(&flags[(layer + 1) * 64 + lane],
                                          __ATOMIC_RELAXED, __HIP_MEMORY_SCOPE_AGENT);
          ok = ok && (va >= (unsigned)t);
        }
        if (__all(ok)) break;
        __builtin_amdgcn_s_sleep(4);
        if ((++spins & 31) == 0)  // progress insurance
          (void)__hip_atomic_load(&flags[layer * 64 + lane],
                                  __ATOMIC_ACQUIRE, __HIP_MEMORY_SCOPE_AGENT);
      }
    }
    __syncthreads();  // release all waves; no fence (h loads are agent-coherent)

    f32x4 acch[4], accx[4];
#pragma unroll
    for (int g = 0; g < 4; ++g) {
      acch[g] = (f32x4){0.f, 0.f, 0.f, 0.f};
      accx[g] = (f32x4){0.f, 0.f, 0.f, 0.f};
    }
    // A-side bases: row = wave*16 + lr (this wave's batch rows), k = lq*8 + ks*32
    const u16* hp = hbuf + (size_t)(layer * 2 + ((t + 1) & 1)) * 65536 +
                    (size_t)(wave * 16 + lr) * 1024 + lq * 8;
    if (layer == 0) {
      DECLH(A) DECLH(B)
      LH(A, 0) LH(B, 1)
      CC8H(A, 0)
      LH(A, 2)
      CC8H(B, 1)
      LH(B, 3)
      CC8H(A, 2)
      CC8H(B, 3)
    } else {
      const u16* xp = hbuf + (size_t)((layer - 1) * 2 + (t & 1)) * 65536 +
                      (size_t)(wave * 16 + lr) * 1024 + lq * 8;
      DECLH(A) DECLX(A) DECLH(B) DECLX(B)
      LH(A, 0) LX(A, 0) LH(B, 1) LX(B, 1)
      CC8HX(A, 0)
      LH(A, 2) LX(A, 2)
      CC8HX(B, 1)
      LH(B, 3) LX(B, 3)
      CC8HX(A, 2)
      CC8HX(B, 3)
    }

    // ---- per-wave transpose: D (lane holds 4 m x 1 j) -> thread (1 m x 4 j) ----
    // write: pb[wave][g][j=lr][m = lq*4 .. +3]; same-wave ds write->read, no barrier
#pragma unroll
    for (int g = 0; g < 4; ++g) {
      f32x4 s = acch[g] + accx[g];
      *(f32x4*)&pb[((size_t)(wave * 4 + g) * 16 + lr) * PB_STRIDE + lq * 4] = s;
    }
    float pre[4][4];  // [d][g]
#pragma unroll
    for (int g = 0; g < 4; ++g)
#pragma unroll
      for (int d = 0; d < 4; ++d)
        pre[d][g] = pb[((size_t)(wave * 4 + g) * 16 + jc + d) * PB_STRIDE + m_loc];
    if (layer == 0) {
#pragma unroll
      for (int d = 0; d < 2; ++d)
#pragma unroll
        for (int g = 0; g < 4; ++g) {
          pre[d][g] += bf2f(xa[d * 4 + g]);
          pre[d + 2][g] += bf2f(xb[d * 4 + g]);
        }
    } else {
#pragma unroll
      for (int d = 0; d < 4; ++d)
#pragma unroll
        for (int g = 0; g < 4; ++g) pre[d][g] += bias_r[g][d];
    }
    float hv[4];
#pragma unroll
    for (int d = 0; d < 4; ++d) {
      float ii = sigmoid_fast(pre[d][0]);
      float ff = sigmoid_fast(pre[d][1]);
      float gg = tanh_fast(pre[d][2]);
      float oo = sigmoid_fast(pre[d][3]);
      float c = ff * creg[d] + ii * gg;
      creg[d] = c;
      hv[d] = oo * tanh_fast(c);
    }
    u64 hpk = ((u64)f2bf(hv[0])) | ((u64)f2bf(hv[1]) << 16) |
              ((u64)f2bf(hv[2]) << 32) | ((u64)f2bf(hv[3]) << 48);
    __hip_atomic_store((u64*)(hbuf + (size_t)(layer * 2 + (t & 1)) * 65536 + (size_t)m * 1024 + j0 + jc),
                       hpk, __ATOMIC_RELAXED, __HIP_MEMORY_SCOPE_AGENT);
    if (layer == 2) {
      float4 yv = { hv[0], hv[1], hv[2], hv[3] };
      *(float4*)(yout + ((size_t)(t * BB + m)) * 1024 + j0 + jc) = yv;
    }
    if (t == TT - 1) {
      float4 hvv = { hv[0], hv[1], hv[2], hv[3] };
      float4 cvv = { creg[0], creg[1], creg[2], creg[3] };
      *(float4*)(hTo + (size_t)layer * 65536 + (size_t)m * 1024 + j0 + jc) = hvv;
      *(float4*)(cTo + (size_t)layer * 65536 + (size_t)m * 1024 + j0 + jc) = cvv;
    }
    // ---- publish: all waves drain vmem at the barrier, then one flag store ----
    __builtin_amdgcn_s_waitcnt(0);
    __syncthreads();
    if (tid == 0)
      __hip_atomic_store(&flags[layer * 64 + blk], (unsigned)(t + 2),
                         __ATOMIC_RELAXED, __HIP_MEMORY_SCOPE_AGENT);
  }
#undef WL
#undef DECLH
#undef DECLX
#undef LH
#undef LX
#undef CKH
#undef CKX
#undef CC8H
#undef CC8HX
}

// ---------------- workspace layout ----------------
#define O_FLAGS ((size_t)0)                          // 3*64 u32 = 768, pad to 1024
#define O_BIAS  ((size_t)1024)                       // 3*4096 f32 = 49152
#define O_HB    (O_BIAS + 49152)                     // 3*2*64*1024 bf16 = 786432
#define O_XBF   (O_HB + 786432)                      // 16384*2048 bf16 = 67108864
#define O_XGI   (O_XBF + 67108864)                   // 16384*4096 bf16 = 134217728
#define O_WIH0  (O_XGI + 134217728)                  // 16777216
#define O_WIH1  (O_WIH0 + 16777216)                  // 8388608
#define O_WIH2  (O_WIH1 + 8388608)
#define O_WHH0  (O_WIH2 + 8388608)
#define O_WHH1  (O_WHH0 + 8388608)
#define O_WHH2  (O_WHH1 + 8388608)

extern "C" void kernel_launch(void* const* d_in, const int* in_sizes, int n_in,
                              void* d_out, int out_size, void* d_ws, size_t ws_size,
                              hipStream_t stream) {
  const float* x = (const float*)d_in[0];
  const float* h0 = (const float*)d_in[1];
  const float* c0 = (const float*)d_in[2];
  char* ws = (char*)d_ws;
  unsigned* flags = (unsigned*)(ws + O_FLAGS);
  float* bias = (float*)(ws + O_BIAS);
  u16* hbuf = (u16*)(ws + O_HB);
  u16* xbf = (u16*)(ws + O_XBF);
  u16* xgi = (u16*)(ws + O_XGI);
  u16* wih[3] = { (u16*)(ws + O_WIH0), (u16*)(ws + O_WIH1), (u16*)(ws + O_WIH2) };
  u16* whh[3] = { (u16*)(ws + O_WHH0), (u16*)(ws + O_WHH1), (u16*)(ws + O_WHH2) };
  float* youtf = (float*)d_out;
  float* hTo = (float*)d_out + (size_t)TT * BB * HH;
  float* cTo = hTo + 3 * BB * HH;

  static int smem_set = 0;
  if (!smem_set) {
    hipFuncSetAttribute((const void*)lstm_pipe,
                        hipFuncAttributeMaxDynamicSharedMemorySize, SMEM_BYTES);
    smem_set = 1;
  }

  hipMemsetAsync(flags, 0, 1024, stream);
  cvt_bf16_k<<<4096, 256, 0, stream>>>(x, xbf, (long)MM * IN_DIM);
  for (int l = 0; l < 3; ++l) {
    long wn = (long)GG * (l == 0 ? IN_DIM : HH);
    cvt_bf16_k<<<2048, 256, 0, stream>>>((const float*)d_in[3 + 4 * l], wih[l], wn);
    cvt_bf16_k<<<2048, 256, 0, stream>>>((const float*)d_in[4 + 4 * l], whh[l], (long)GG * HH);
    bias_sum_k<<<16, 256, 0, stream>>>((const float*)d_in[5 + 4 * l],
                                       (const float*)d_in[6 + 4 * l], bias + l * GG, GG);
  }
  gemm_bt_bias<<<dim3(128, 32), 256, 0, stream>>>(xbf, wih[0], bias, xgi, IN_DIM);
  lstm_pipe<<<NBLK, 256, SMEM_BYTES, stream>>>(whh[0], whh[1], whh[2], wih[1], wih[2],
                                               xgi, bias, h0, c0, hbuf, youtf, hTo, cTo, flags);
}